// Round 4
// baseline (611.433 us; speedup 1.0000x reference)
//
#include <hip/hip_runtime.h>

#define N_NODES 100000
#define N_EDGES 3200000
#define DIM 256

typedef _Float16 half_t;
typedef __attribute__((ext_vector_type(4))) _Float16 half4;
typedef __attribute__((ext_vector_type(8))) _Float16 half8;
typedef __attribute__((ext_vector_type(4))) float floatx4;
typedef __attribute__((ext_vector_type(4))) int intx4;

// ---------------------------------------------------------------------------
// W cast+transpose: wT[n][k] = (f16) w[k][n].  256x256, grid(8,8) x 256 thr.
// ---------------------------------------------------------------------------
__global__ __launch_bounds__(256) void castw_kernel(const float* __restrict__ w,
                                                    half_t* __restrict__ wT) {
    __shared__ float tile[32][33];
    int bk = blockIdx.x * 32;  // k block
    int bn = blockIdx.y * 32;  // n block
    int tx = threadIdx.x & 31, ty = threadIdx.x >> 5;  // 32 x 8
#pragma unroll
    for (int i = 0; i < 4; i++)
        tile[ty + i * 8][tx] = w[(size_t)(bk + ty + i * 8) * DIM + bn + tx];
    __syncthreads();
#pragma unroll
    for (int i = 0; i < 4; i++)
        wT[(size_t)(bn + ty + i * 8) * DIM + bk + tx] = (half_t)tile[tx][ty + i * 8];
}

// ---------------------------------------------------------------------------
// MFMA GEMM: support[M,256] (f16) = x[M,256] (fp32) @ wT^T.
// Block tile 128x256 (full N in one pass -> A read once), 512 thr / 8 waves.
// A loaded non-temporally (streamed once; don't pollute L2).
// ---------------------------------------------------------------------------
#define BM 128
#define BK 32
#define LDK 40

__global__ __launch_bounds__(512) void gemm_f16_kernel(const float* __restrict__ A,
                                                       const half_t* __restrict__ BT,
                                                       half_t* __restrict__ C, int M) {
    __shared__ half_t As[BM][LDK];
    __shared__ half_t Bs[256][LDK];

    const int tid = threadIdx.x;
    const int wid = tid >> 6, lane = tid & 63;
    const int wm = wid & 1, wn = wid >> 1;   // 2 x 4
    const int row0 = blockIdx.x * BM;
    const int lr = lane & 15;
    const int quad = lane >> 4;

    floatx4 acc[4][4] = {};

    // A staging map: 128 rows x 32 k fp32 = 1024 float4; thread -> 2 float4
    const int ar = tid >> 2;
    const int ac = (tid & 3) * 8;
    const bool avalid = (row0 + ar) < M;
    const float* aptr = A + (size_t)(row0 + ar) * DIM + ac;

    for (int k0 = 0; k0 < DIM; k0 += BK) {
        // ---- stage A (fp32 -> f16): 128x32 ----
        {
            const floatx4* src = (const floatx4*)(aptr + k0);
            half_t* dst = &As[ar][ac];
#pragma unroll
            for (int i = 0; i < 2; i++) {
                floatx4 v = avalid ? __builtin_nontemporal_load(src + i)
                                   : (floatx4){0.f, 0.f, 0.f, 0.f};
                half4 h;
                h.x = (half_t)v.x; h.y = (half_t)v.y;
                h.z = (half_t)v.z; h.w = (half_t)v.w;
                ((half4*)dst)[i] = h;
            }
        }
        // ---- stage B (f16 copy): 256 n-rows x 32 k = 1024 16B chunks ----
        {
#pragma unroll
            for (int i = 0; i < 2; i++) {
                int ch = tid + i * 512;
                int r = ch >> 2, cb = (ch & 3) * 8;
                half8 v = *(const half8*)(BT + (size_t)r * DIM + k0 + cb);
                *(half8*)&Bs[r][cb] = v;
            }
        }
        __syncthreads();

        half8 a[4], b[4];
#pragma unroll
        for (int i = 0; i < 4; i++)
            a[i] = *(const half8*)&As[wm * 64 + i * 16 + lr][quad * 8];
#pragma unroll
        for (int j = 0; j < 4; j++)
            b[j] = *(const half8*)&Bs[wn * 64 + j * 16 + lr][quad * 8];
#pragma unroll
        for (int i = 0; i < 4; i++)
#pragma unroll
            for (int j = 0; j < 4; j++)
                acc[i][j] = __builtin_amdgcn_mfma_f32_16x16x32_f16(a[i], b[j], acc[i][j], 0, 0, 0);
        __syncthreads();
    }

#pragma unroll
    for (int i = 0; i < 4; i++) {
#pragma unroll
        for (int j = 0; j < 4; j++) {
            int gc = wn * 64 + j * 16 + lr;
            int grb = row0 + wm * 64 + i * 16 + quad * 4;
#pragma unroll
            for (int r = 0; r < 4; r++) {
                int gr = grb + r;
                if (gr < M) C[(size_t)gr * DIM + gc] = (half_t)acc[i][j][r];
            }
        }
    }
}

// ---------------------------------------------------------------------------
// CSR construction via 2-level counting sort, no pre-histogram pass.
// Bucket = row >> 8 (391 buckets). Each bucket owns a FIXED-CAPACITY region
// of CAP edges in the d_out scratch; cursors start at 0 (memset), so the
// hist+scan prepass is eliminated. Expected bucket count 8192 +- 90;
// CAP=16384 is a ~90-sigma bound.
// ---------------------------------------------------------------------------
#define NBUCK 391
#define CAP 16384
#define EPB 4096                         // edges per scatter block
#define NEB ((N_EDGES + EPB - 1) / EPB)  // 782 blocks

// Pass 1: scatter edges into fixed bucket regions (LDS-aggregated cursors).
// tmp record: .x = ((row & 255) << 17) | col   (col < 2^17), .y = val bits
__global__ __launch_bounds__(256) void bucket_scatter_kernel(const int* __restrict__ erow,
                                                             const int* __restrict__ ecol,
                                                             const float* __restrict__ eval,
                                                             int* __restrict__ bcursor,
                                                             int2* __restrict__ tmp) {
    __shared__ int lh[NBUCK];
    __shared__ int lbase[NBUCK];
    for (int b = threadIdx.x; b < NBUCK; b += 256) lh[b] = 0;
    __syncthreads();

    int base4 = blockIdx.x * (EPB / 4);
    // phase 1: local histogram (erow stream, NT)
#pragma unroll
    for (int i = 0; i < 4; i++) {
        int idx4 = base4 + i * 256 + threadIdx.x;
        if (idx4 < N_EDGES / 4) {
            intx4 r4 = __builtin_nontemporal_load((const intx4*)erow + idx4);
            atomicAdd(&lh[r4.x >> 8], 1);
            atomicAdd(&lh[r4.y >> 8], 1);
            atomicAdd(&lh[r4.z >> 8], 1);
            atomicAdd(&lh[r4.w >> 8], 1);
        }
    }
    __syncthreads();
    // reserve contiguous chunks inside each bucket's fixed region
    for (int b = threadIdx.x; b < NBUCK; b += 256) {
        int c = lh[b];
        lbase[b] = c ? (b * CAP + atomicAdd(&bcursor[b * 16], c)) : 0;
        lh[b] = 0;   // becomes local rank cursor
    }
    __syncthreads();

    // phase 2: re-read (erow L2-hot) & scatter
#define SCAT(R, C, V)                                                     \
    {                                                                     \
        int _r = (R), _c = (C);                                           \
        int _b = _r >> 8;                                                 \
        int _rank = atomicAdd(&lh[_b], 1);                                \
        tmp[lbase[_b] + _rank] =                                          \
            make_int2(((_r & 255) << 17) | _c, __float_as_int(V));        \
    }
#pragma unroll
    for (int i = 0; i < 4; i++) {
        int idx4 = base4 + i * 256 + threadIdx.x;
        if (idx4 < N_EDGES / 4) {
            intx4 r4 = __builtin_nontemporal_load((const intx4*)erow + idx4);
            intx4 c4 = __builtin_nontemporal_load((const intx4*)ecol + idx4);
            floatx4 v4 = __builtin_nontemporal_load((const floatx4*)eval + idx4);
            SCAT(r4.x, c4.x, v4.x);
            SCAT(r4.y, c4.y, v4.y);
            SCAT(r4.z, c4.z, v4.z);
            SCAT(r4.w, c4.w, v4.w);
        }
    }
#undef SCAT
}

// Pass 1b: scan 391 bucket counts -> output bases
__global__ __launch_bounds__(512) void scan_buckets_kernel(const int* __restrict__ bcnt,
                                                           int* __restrict__ bbase,
                                                           int* __restrict__ offsets) {
    __shared__ int s[512];
    int t = threadIdx.x;
    int v = (t < NBUCK) ? bcnt[t * 16] : 0;
    s[t] = v;
    __syncthreads();
    for (int off = 1; off < 512; off <<= 1) {
        int u = (t >= off) ? s[t - off] : 0;
        __syncthreads();
        s[t] += u;
        __syncthreads();
    }
    if (t < NBUCK) bbase[t] = s[t] - v;   // exclusive prefix
    if (t == 0) { bbase[NBUCK] = N_EDGES; offsets[N_NODES] = N_EDGES; }
}

// Pass 2: one block per bucket. LDS hist + scan of 256 local rows ->
// offsets + in-bucket CSR scatter (64 KB destination window, no global atomics)
__global__ __launch_bounds__(256) void bucket_to_csr_kernel(const int2* __restrict__ tmp,
                                                            const int* __restrict__ bcnt,
                                                            const int* __restrict__ bbase,
                                                            int* __restrict__ offsets,
                                                            int2* __restrict__ sedge) {
    __shared__ int lh[256];
    __shared__ int s[256];
    const int b = blockIdx.x;
    const int t = threadIdx.x;
    const int cnt = bcnt[b * 16];
    const int obase = bbase[b];
    const int2* src = tmp + (size_t)b * CAP;

    lh[t] = 0;
    __syncthreads();
    for (int e = t; e < cnt; e += 256)
        atomicAdd(&lh[src[e].x >> 17], 1);
    __syncthreads();

    int c = lh[t];
    s[t] = c;
    __syncthreads();
    for (int off = 1; off < 256; off <<= 1) {
        int u = (t >= off) ? s[t - off] : 0;
        __syncthreads();
        s[t] += u;
        __syncthreads();
    }
    int ex = s[t] - c;
    int row = (b << 8) + t;
    if (row < N_NODES) offsets[row] = obase + ex;
    lh[t] = ex;   // local cursor
    __syncthreads();

    for (int e = t; e < cnt; e += 256) {
        int2 q = src[e];
        int lr = q.x >> 17;
        int rank = atomicAdd(&lh[lr], 1);
        sedge[obase + rank] = make_int2(q.x & 0x1FFFF, q.y);
    }
}

// ---------------------------------------------------------------------------
// CSR SpMM: one wave per row; half-wave per edge (32 lanes x 16 B = full row).
// int4 NT edge loads + 16-edge unroll = 8 gathers in flight/lane.
// NT loads for the edge stream and NT stores for out keep L2 free for the
// support gather working set (51.2 MB).
// ---------------------------------------------------------------------------
__global__ __launch_bounds__(256, 8) void spmm_kernel(const half_t* __restrict__ support,
                                                      const int* __restrict__ offsets,
                                                      const int2* __restrict__ edges,
                                                      float* __restrict__ out) {
    int row = (blockIdx.x * blockDim.x + threadIdx.x) >> 6;
    if (row >= N_NODES) return;
    int lane = threadIdx.x & 63;
    int h = lane >> 5;   // which half-wave
    int j = lane & 31;   // 16 B chunk within the 512 B support row

    int beg = offsets[row];
    int end = offsets[row + 1];

    float acc[8] = {0.f, 0.f, 0.f, 0.f, 0.f, 0.f, 0.f, 0.f};
    int e = beg;

    // alignment peel: make e even so int4 edge loads are 16B-aligned
    if ((e & 1) && e < end) {
        int2 q0 = edges[e];
        half8 s0 = *(const half8*)(support + (size_t)q0.x * DIM + j * 8);
        float v0 = (h == 0) ? __int_as_float(q0.y) : 0.f;
#pragma unroll
        for (int d = 0; d < 8; d++) acc[d] += v0 * (float)s0[d];
        e++;
    }

    // main: 16 edges/iter; half h takes pairs {e+2h, e+2h+1} of each quad
    for (; e + 15 < end; e += 16) {
        intx4 pa = __builtin_nontemporal_load((const intx4*)(edges + e + 2 * h));
        intx4 pb = __builtin_nontemporal_load((const intx4*)(edges + e + 4 + 2 * h));
        intx4 pc = __builtin_nontemporal_load((const intx4*)(edges + e + 8 + 2 * h));
        intx4 pd = __builtin_nontemporal_load((const intx4*)(edges + e + 12 + 2 * h));
        half8 s0 = *(const half8*)(support + (size_t)pa.x * DIM + j * 8);
        half8 s1 = *(const half8*)(support + (size_t)pa.z * DIM + j * 8);
        half8 s2 = *(const half8*)(support + (size_t)pb.x * DIM + j * 8);
        half8 s3 = *(const half8*)(support + (size_t)pb.z * DIM + j * 8);
        half8 s4 = *(const half8*)(support + (size_t)pc.x * DIM + j * 8);
        half8 s5 = *(const half8*)(support + (size_t)pc.z * DIM + j * 8);
        half8 s6 = *(const half8*)(support + (size_t)pd.x * DIM + j * 8);
        half8 s7 = *(const half8*)(support + (size_t)pd.z * DIM + j * 8);
        float v0 = __int_as_float(pa.y), v1 = __int_as_float(pa.w);
        float v2 = __int_as_float(pb.y), v3 = __int_as_float(pb.w);
        float v4 = __int_as_float(pc.y), v5 = __int_as_float(pc.w);
        float v6 = __int_as_float(pd.y), v7 = __int_as_float(pd.w);
#pragma unroll
        for (int d = 0; d < 8; d++)
            acc[d] += v0 * (float)s0[d] + v1 * (float)s1[d]
                    + v2 * (float)s2[d] + v3 * (float)s3[d]
                    + v4 * (float)s4[d] + v5 * (float)s5[d]
                    + v6 * (float)s6[d] + v7 * (float)s7[d];
    }
    // pair tail
    for (; e + 1 < end; e += 2) {
        int2 q0 = edges[e + h];
        half8 s0 = *(const half8*)(support + (size_t)q0.x * DIM + j * 8);
        float v0 = __int_as_float(q0.y);
#pragma unroll
        for (int d = 0; d < 8; d++) acc[d] += v0 * (float)s0[d];
    }
    // odd tail: both halves load edge e; half 1 contributes 0
    if (e < end) {
        int2 q0 = edges[e];
        half8 s0 = *(const half8*)(support + (size_t)q0.x * DIM + j * 8);
        float v0 = (h == 0) ? __int_as_float(q0.y) : 0.f;
#pragma unroll
        for (int d = 0; d < 8; d++) acc[d] += v0 * (float)s0[d];
    }

    // cross-half combine: lane (h, j) keeps dims j*8 + h*4 .. +4
    float r0, r1, r2, r3, g0, g1, g2, g3;
    if (h == 0) {
        r0 = acc[0]; r1 = acc[1]; r2 = acc[2]; r3 = acc[3];
        g0 = acc[4]; g1 = acc[5]; g2 = acc[6]; g3 = acc[7];
    } else {
        r0 = acc[4]; r1 = acc[5]; r2 = acc[6]; r3 = acc[7];
        g0 = acc[0]; g1 = acc[1]; g2 = acc[2]; g3 = acc[3];
    }
    r0 += __shfl_xor(g0, 32, 64);
    r1 += __shfl_xor(g1, 32, 64);
    r2 += __shfl_xor(g2, 32, 64);
    r3 += __shfl_xor(g3, 32, 64);

    floatx4 res = {r0, r1, r2, r3};
    __builtin_nontemporal_store(res, (floatx4*)(out + (size_t)row * DIM + j * 8 + h * 4));
}

extern "C" void kernel_launch(void* const* d_in, const int* in_sizes, int n_in,
                              void* d_out, int out_size, void* d_ws, size_t ws_size,
                              hipStream_t stream) {
    const float* x    = (const float*)d_in[0];
    const float* w    = (const float*)d_in[1];
    const int*   erow = (const int*)d_in[2];
    const int*   ecol = (const int*)d_in[3];
    const float* eval = (const float*)d_in[4];
    float* out = (float*)d_out;

    // workspace layout
    char* ws = (char*)d_ws;
    half_t* support = (half_t*)ws;                       // 51,200,000 B
    int*    offsets = (int*)(ws + 51200000);             //    400,004 B
    int2*   sedge   = (int2*)(ws + 51600128);            // 25,600,000 B (col,val)
    half_t* wT      = (half_t*)(ws + 77200128);          //    131,072 B
    int*    bcnt    = (int*)(ws + 77331200);             // 391*64 B (stride-16 cursors)
    int*    bbase   = (int*)(ws + 77356224);             // 392*4 B
    // bucket-major tmp edges live in d_out: 391 regions x CAP=16384 x 8 B
    // = 51,249,152 B <= out_size (102,400,000 B); dead before spmm writes out.
    int2*   tmp     = (int2*)d_out;

    hipMemsetAsync(bcnt, 0, NBUCK * 16 * sizeof(int), stream);

    castw_kernel<<<dim3(8, 8), 256, 0, stream>>>(w, wT);

    dim3 ggrid((N_NODES + BM - 1) / BM, 1);
    gemm_f16_kernel<<<ggrid, 512, 0, stream>>>(x, wT, support, N_NODES);

    bucket_scatter_kernel<<<NEB, 256, 0, stream>>>(erow, ecol, eval, bcnt, tmp);
    scan_buckets_kernel<<<1, 512, 0, stream>>>(bcnt, bbase, offsets);
    bucket_to_csr_kernel<<<NBUCK, 256, 0, stream>>>(tmp, bcnt, bbase, offsets, sedge);

    spmm_kernel<<<(N_NODES * 64 + 255) / 256, 256, 0, stream>>>(support, offsets,
                                                                sedge, out);
}

// Round 7
// 558.411 us; speedup vs baseline: 1.0950x; 1.0950x over previous
//
#include <hip/hip_runtime.h>

#define N_NODES 100000
#define N_EDGES 3200000
#define DIM 256

typedef _Float16 half_t;
typedef __attribute__((ext_vector_type(4))) _Float16 half4;
typedef __attribute__((ext_vector_type(8))) _Float16 half8;
typedef __attribute__((ext_vector_type(4))) float floatx4;

// ---------------------------------------------------------------------------
// W cast+transpose: wT[n][k] = (f16) w[k][n].  256x256, grid(8,8) x 256 thr.
// ---------------------------------------------------------------------------
__global__ __launch_bounds__(256) void castw_kernel(const float* __restrict__ w,
                                                    half_t* __restrict__ wT) {
    __shared__ float tile[32][33];
    int bk = blockIdx.x * 32;  // k block
    int bn = blockIdx.y * 32;  // n block
    int tx = threadIdx.x & 31, ty = threadIdx.x >> 5;  // 32 x 8
#pragma unroll
    for (int i = 0; i < 4; i++)
        tile[ty + i * 8][tx] = w[(size_t)(bk + ty + i * 8) * DIM + bn + tx];
    __syncthreads();
#pragma unroll
    for (int i = 0; i < 4; i++)
        wT[(size_t)(bn + ty + i * 8) * DIM + bk + tx] = (half_t)tile[tx][ty + i * 8];
}

// ---------------------------------------------------------------------------
// MFMA GEMM: support[M,256] (f16) = x[M,256] (fp32) @ wT^T.
// Block tile 128x256 (full N in one pass -> A read once), 512 thr / 8 waves.
// ---------------------------------------------------------------------------
#define BM 128
#define BK 32
#define LDK 40

__global__ __launch_bounds__(512) void gemm_f16_kernel(const float* __restrict__ A,
                                                       const half_t* __restrict__ BT,
                                                       half_t* __restrict__ C, int M) {
    __shared__ half_t As[BM][LDK];
    __shared__ half_t Bs[256][LDK];

    const int tid = threadIdx.x;
    const int wid = tid >> 6, lane = tid & 63;
    const int wm = wid & 1, wn = wid >> 1;   // 2 x 4
    const int row0 = blockIdx.x * BM;
    const int lr = lane & 15;
    const int quad = lane >> 4;

    floatx4 acc[4][4] = {};

    // A staging map: 128 rows x 32 k fp32 = 1024 float4; thread -> 2 float4
    const int ar = tid >> 2;
    const int ac = (tid & 3) * 8;
    const bool avalid = (row0 + ar) < M;
    const float* aptr = A + (size_t)(row0 + ar) * DIM + ac;

    for (int k0 = 0; k0 < DIM; k0 += BK) {
        // ---- stage A (fp32 -> f16): 128x32 ----
        {
            const float4* src = (const float4*)(aptr + k0);
            half_t* dst = &As[ar][ac];
#pragma unroll
            for (int i = 0; i < 2; i++) {
                float4 v = avalid ? src[i] : make_float4(0.f, 0.f, 0.f, 0.f);
                half4 h;
                h.x = (half_t)v.x; h.y = (half_t)v.y;
                h.z = (half_t)v.z; h.w = (half_t)v.w;
                ((half4*)dst)[i] = h;
            }
        }
        // ---- stage B (f16 copy): 256 n-rows x 32 k = 1024 16B chunks ----
        {
#pragma unroll
            for (int i = 0; i < 2; i++) {
                int ch = tid + i * 512;
                int r = ch >> 2, cb = (ch & 3) * 8;
                half8 v = *(const half8*)(BT + (size_t)r * DIM + k0 + cb);
                *(half8*)&Bs[r][cb] = v;
            }
        }
        __syncthreads();

        half8 a[4], b[4];
#pragma unroll
        for (int i = 0; i < 4; i++)
            a[i] = *(const half8*)&As[wm * 64 + i * 16 + lr][quad * 8];
#pragma unroll
        for (int j = 0; j < 4; j++)
            b[j] = *(const half8*)&Bs[wn * 64 + j * 16 + lr][quad * 8];
#pragma unroll
        for (int i = 0; i < 4; i++)
#pragma unroll
            for (int j = 0; j < 4; j++)
                acc[i][j] = __builtin_amdgcn_mfma_f32_16x16x32_f16(a[i], b[j], acc[i][j], 0, 0, 0);
        __syncthreads();
    }

#pragma unroll
    for (int i = 0; i < 4; i++) {
#pragma unroll
        for (int j = 0; j < 4; j++) {
            int gc = wn * 64 + j * 16 + lr;
            int grb = row0 + wm * 64 + i * 16 + quad * 4;
#pragma unroll
            for (int r = 0; r < 4; r++) {
                int gr = grb + r;
                if (gr < M) C[(size_t)gr * DIM + gc] = (half_t)acc[i][j][r];
            }
        }
    }
}

// ---------------------------------------------------------------------------
// CSR construction via 2-level counting sort, no pre-histogram pass.
// Bucket = row >> 8 (391 buckets). Each bucket owns a FIXED-CAPACITY region
// of CAP edges in the d_out scratch; cursors start at 0 (memset).
// Expected bucket count 8192 +- 90; CAP=16384 is a ~90-sigma bound.
// ---------------------------------------------------------------------------
#define NBUCK 391
#define CAP 16384
#define EPB 4096                         // edges per scatter block
#define NEB ((N_EDGES + EPB - 1) / EPB)  // 782 blocks

// Pass 1: scatter edges into fixed bucket regions (LDS-aggregated cursors).
// tmp record: .x = ((row & 255) << 17) | col   (col < 2^17), .y = val bits
__global__ __launch_bounds__(256) void bucket_scatter_kernel(const int* __restrict__ erow,
                                                             const int* __restrict__ ecol,
                                                             const float* __restrict__ eval,
                                                             int* __restrict__ bcursor,
                                                             int2* __restrict__ tmp) {
    __shared__ int lh[NBUCK];
    __shared__ int lbase[NBUCK];
    for (int b = threadIdx.x; b < NBUCK; b += 256) lh[b] = 0;
    __syncthreads();

    int base4 = blockIdx.x * (EPB / 4);
    // phase 1: local histogram
#pragma unroll
    for (int i = 0; i < 4; i++) {
        int idx4 = base4 + i * 256 + threadIdx.x;
        if (idx4 < N_EDGES / 4) {
            int4 r4 = ((const int4*)erow)[idx4];
            atomicAdd(&lh[r4.x >> 8], 1);
            atomicAdd(&lh[r4.y >> 8], 1);
            atomicAdd(&lh[r4.z >> 8], 1);
            atomicAdd(&lh[r4.w >> 8], 1);
        }
    }
    __syncthreads();
    // reserve contiguous chunks inside each bucket's fixed region
    for (int b = threadIdx.x; b < NBUCK; b += 256) {
        int c = lh[b];
        lbase[b] = c ? (b * CAP + atomicAdd(&bcursor[b * 16], c)) : 0;
        lh[b] = 0;   // becomes local rank cursor
    }
    __syncthreads();

    // phase 2: re-read (L2-hot) & scatter
#define SCAT(R, C, V)                                                     \
    {                                                                     \
        int _r = (R), _c = (C);                                           \
        int _b = _r >> 8;                                                 \
        int _rank = atomicAdd(&lh[_b], 1);                                \
        tmp[lbase[_b] + _rank] =                                          \
            make_int2(((_r & 255) << 17) | _c, __float_as_int(V));        \
    }
#pragma unroll
    for (int i = 0; i < 4; i++) {
        int idx4 = base4 + i * 256 + threadIdx.x;
        if (idx4 < N_EDGES / 4) {
            int4 r4 = ((const int4*)erow)[idx4];
            int4 c4 = ((const int4*)ecol)[idx4];
            float4 v4 = ((const float4*)eval)[idx4];
            SCAT(r4.x, c4.x, v4.x);
            SCAT(r4.y, c4.y, v4.y);
            SCAT(r4.z, c4.z, v4.z);
            SCAT(r4.w, c4.w, v4.w);
        }
    }
#undef SCAT
}

// Pass 1b: scan 391 bucket counts -> output bases
__global__ __launch_bounds__(512) void scan_buckets_kernel(const int* __restrict__ bcnt,
                                                           int* __restrict__ bbase,
                                                           int* __restrict__ offsets) {
    __shared__ int s[512];
    int t = threadIdx.x;
    int v = (t < NBUCK) ? bcnt[t * 16] : 0;
    s[t] = v;
    __syncthreads();
    for (int off = 1; off < 512; off <<= 1) {
        int u = (t >= off) ? s[t - off] : 0;
        __syncthreads();
        s[t] += u;
        __syncthreads();
    }
    if (t < NBUCK) bbase[t] = s[t] - v;   // exclusive prefix
    if (t == 0) { bbase[NBUCK] = N_EDGES; offsets[N_NODES] = N_EDGES; }
}

// Pass 2: one block per bucket. LDS hist + scan of 256 local rows ->
// offsets + in-bucket CSR scatter (64 KB destination window, no global atomics)
__global__ __launch_bounds__(256) void bucket_to_csr_kernel(const int2* __restrict__ tmp,
                                                            const int* __restrict__ bcnt,
                                                            const int* __restrict__ bbase,
                                                            int* __restrict__ offsets,
                                                            int2* __restrict__ sedge) {
    __shared__ int lh[256];
    __shared__ int s[256];
    const int b = blockIdx.x;
    const int t = threadIdx.x;
    const int cnt = bcnt[b * 16];
    const int obase = bbase[b];
    const int2* src = tmp + (size_t)b * CAP;

    lh[t] = 0;
    __syncthreads();
    for (int e = t; e < cnt; e += 256)
        atomicAdd(&lh[src[e].x >> 17], 1);
    __syncthreads();

    int c = lh[t];
    s[t] = c;
    __syncthreads();
    for (int off = 1; off < 256; off <<= 1) {
        int u = (t >= off) ? s[t - off] : 0;
        __syncthreads();
        s[t] += u;
        __syncthreads();
    }
    int ex = s[t] - c;
    int row = (b << 8) + t;
    if (row < N_NODES) offsets[row] = obase + ex;
    lh[t] = ex;   // local cursor
    __syncthreads();

    for (int e = t; e < cnt; e += 256) {
        int2 q = src[e];
        int lr = q.x >> 17;
        int rank = atomicAdd(&lh[lr], 1);
        sedge[obase + rank] = make_int2(q.x & 0x1FFFF, q.y);
    }
}

// ---------------------------------------------------------------------------
// CSR SpMM, D-split: one pass handles 128 dims (256 B slice per node).
// One wave per row; QUARTER-wave (16 lanes x 16 B) per edge -> 4 edges in
// parallel; 16-edge unroll = 4 gathers in flight/lane. Halving lines/edge
// (8 -> 4) doubles L2 line lifetime -> higher hit rate on the support gather.
// Cross-group shfl_xor reduce; no atomics. Two sequential launches (d0=0,128)
// so each pass's working set stays at 4 lines/edge machine-wide.
// ---------------------------------------------------------------------------
__global__ __launch_bounds__(256) void spmm_kernel(const half_t* __restrict__ support,
                                                   const int* __restrict__ offsets,
                                                   const int2* __restrict__ edges,
                                                   float* __restrict__ out, int d0) {
    int row = (blockIdx.x * blockDim.x + threadIdx.x) >> 6;
    if (row >= N_NODES) return;
    int lane = threadIdx.x & 63;
    int g = lane >> 4;    // edge group 0..3
    int j = lane & 15;    // 16 B chunk within the 256 B slice

    const half_t* sup = support + d0;
    int beg = offsets[row];
    int end = offsets[row + 1];

    float acc[8] = {0.f, 0.f, 0.f, 0.f, 0.f, 0.f, 0.f, 0.f};
    int e = beg;

    // alignment peel: make e even so int4 edge loads are 16B-aligned
    if ((e & 1) && e < end) {
        int2 q = edges[e];
        half8 s = *(const half8*)(sup + (size_t)q.x * DIM + j * 8);
        float v = (g == 0) ? __int_as_float(q.y) : 0.f;
#pragma unroll
        for (int d = 0; d < 8; d++) acc[d] += v * (float)s[d];
        e++;
    }

    // main: 16 edges/iter; group g takes pairs {e+2g, e+2g+1}, {e+8+2g, +1}
    for (; e + 15 < end; e += 16) {
        int4 pa = *(const int4*)(edges + e + 2 * g);
        int4 pb = *(const int4*)(edges + e + 8 + 2 * g);
        half8 s0 = *(const half8*)(sup + (size_t)pa.x * DIM + j * 8);
        half8 s1 = *(const half8*)(sup + (size_t)pa.z * DIM + j * 8);
        half8 s2 = *(const half8*)(sup + (size_t)pb.x * DIM + j * 8);
        half8 s3 = *(const half8*)(sup + (size_t)pb.z * DIM + j * 8);
        float v0 = __int_as_float(pa.y), v1 = __int_as_float(pa.w);
        float v2 = __int_as_float(pb.y), v3 = __int_as_float(pb.w);
#pragma unroll
        for (int d = 0; d < 8; d++)
            acc[d] += v0 * (float)s0[d] + v1 * (float)s1[d]
                    + v2 * (float)s2[d] + v3 * (float)s3[d];
    }
    // 8-edge step
    if (e + 7 < end) {
        int4 pa = *(const int4*)(edges + e + 2 * g);
        half8 s0 = *(const half8*)(sup + (size_t)pa.x * DIM + j * 8);
        half8 s1 = *(const half8*)(sup + (size_t)pa.z * DIM + j * 8);
        float v0 = __int_as_float(pa.y), v1 = __int_as_float(pa.w);
#pragma unroll
        for (int d = 0; d < 8; d++)
            acc[d] += v0 * (float)s0[d] + v1 * (float)s1[d];
        e += 8;
    }
    // scalar tail (<8 edges): all groups gather (coalesced dup), only g0 counts
    for (; e < end; e++) {
        int2 q = edges[e];
        half8 s = *(const half8*)(sup + (size_t)q.x * DIM + j * 8);
        float v = (g == 0) ? __int_as_float(q.y) : 0.f;
#pragma unroll
        for (int d = 0; d < 8; d++) acc[d] += v * (float)s[d];
    }

    // reduce across the 4 edge-groups (same j)
#pragma unroll
    for (int d = 0; d < 8; d++) {
        acc[d] += __shfl_xor(acc[d], 16, 64);
        acc[d] += __shfl_xor(acc[d], 32, 64);
    }

    // lanes 0..31 write the 512 B f32 slice: lane (hi,j) -> dims j*8 + hi*4
    if (lane < 32) {
        int hi = lane >> 4;
        floatx4 res = {acc[hi * 4 + 0], acc[hi * 4 + 1],
                       acc[hi * 4 + 2], acc[hi * 4 + 3]};
        *(floatx4*)(out + (size_t)row * DIM + d0 + j * 8 + hi * 4) = res;
    }
}

extern "C" void kernel_launch(void* const* d_in, const int* in_sizes, int n_in,
                              void* d_out, int out_size, void* d_ws, size_t ws_size,
                              hipStream_t stream) {
    const float* x    = (const float*)d_in[0];
    const float* w    = (const float*)d_in[1];
    const int*   erow = (const int*)d_in[2];
    const int*   ecol = (const int*)d_in[3];
    const float* eval = (const float*)d_in[4];
    float* out = (float*)d_out;

    // workspace layout (ends at 77,357,792 B — same as round-3 green run)
    char* ws = (char*)d_ws;
    half_t* support = (half_t*)ws;                       // 51,200,000 B
    int*    offsets = (int*)(ws + 51200000);             //    400,004 B
    int2*   sedge   = (int2*)(ws + 51600128);            // 25,600,000 B (col,val)
    half_t* wT      = (half_t*)(ws + 77200128);          //    131,072 B
    int*    bcnt    = (int*)(ws + 77331200);             // 391*64 B (stride-16 cursors)
    int*    bbase   = (int*)(ws + 77356224);             // 392*4 B
    // bucket-major tmp edges live in d_out: 391 regions x CAP=16384 x 8 B
    // = 51,249,152 B <= out_size (102,400,000 B); dead before spmm writes out.
    int2*   tmp     = (int2*)d_out;

    hipMemsetAsync(bcnt, 0, NBUCK * 16 * sizeof(int), stream);

    castw_kernel<<<dim3(8, 8), 256, 0, stream>>>(w, wT);

    dim3 ggrid((N_NODES + BM - 1) / BM, 1);
    gemm_f16_kernel<<<ggrid, 512, 0, stream>>>(x, wT, support, N_NODES);

    bucket_scatter_kernel<<<NEB, 256, 0, stream>>>(erow, ecol, eval, bcnt, tmp);
    scan_buckets_kernel<<<1, 512, 0, stream>>>(bcnt, bbase, offsets);
    bucket_to_csr_kernel<<<NBUCK, 256, 0, stream>>>(tmp, bcnt, bbase, offsets, sedge);

    int sgrid = (N_NODES * 64 + 255) / 256;
    spmm_kernel<<<sgrid, 256, 0, stream>>>(support, offsets, sedge, out, 0);
    spmm_kernel<<<sgrid, 256, 0, stream>>>(support, offsets, sedge, out, 128);
}